// Round 5
// baseline (676.483 us; speedup 1.0000x reference)
//
#include <hip/hip_runtime.h>
#include <hip/hip_bf16.h>

#define VOCAB 50000
#define DD 256
#define NCLS 10
#define BB 64
#define SS 512
#define HH 512
#define K3D 768

typedef __attribute__((ext_vector_type(8))) short bf16x8;
typedef __attribute__((ext_vector_type(8))) unsigned short ush8;
typedef __attribute__((ext_vector_type(4))) float f32x4;

static __device__ __forceinline__ unsigned short f2bf(float f) {
    __hip_bfloat16 h = __float2bfloat16(f);
    return *reinterpret_cast<unsigned short*>(&h);
}

// ---------------------------------------------------------------------------
// Kernel P: prep — convert conv_w, build Wscat (bf16 concat Wsl|Wsr), biascat.
// grid = 192 (convw) + 64 (wscat) + 1 (biascat) = 257 blocks.
// ---------------------------------------------------------------------------
__global__ __launch_bounds__(256) void prep_kernel(
    const float* __restrict__ conv_w,
    const float* __restrict__ Wsl, const float* __restrict__ Wsr,
    const float* __restrict__ bsl, const float* __restrict__ bl,
    const float* __restrict__ bsr, const float* __restrict__ br,
    unsigned short* __restrict__ convwb,
    unsigned short* __restrict__ wscat,
    float* __restrict__ biascat)
{
    const int bid = blockIdx.x;
    if (bid < 192) {
        const int g = bid * 256 + threadIdx.x;          // 8-elt chunk of conv_w
        const float* src = conv_w + (size_t)g * 8;
        const float4 v0 = *(const float4*)(src);
        const float4 v1 = *(const float4*)(src + 4);
        ush8 o;
        o[0]=f2bf(v0.x); o[1]=f2bf(v0.y); o[2]=f2bf(v0.z); o[3]=f2bf(v0.w);
        o[4]=f2bf(v1.x); o[5]=f2bf(v1.y); o[6]=f2bf(v1.z); o[7]=f2bf(v1.w);
        *(ush8*)(convwb + (size_t)g * 8) = o;
    } else if (bid < 256) {
        const int g = (bid - 192) * 256 + threadIdx.x;  // 8-elt chunk of wscat
        const int row = g >> 5, d0 = (g & 31) * 8;
        const float* src = (row < 256 ? Wsl + (size_t)row * DD
                                      : Wsr + (size_t)(row - 256) * DD) + d0;
        const float4 v0 = *(const float4*)(src);
        const float4 v1 = *(const float4*)(src + 4);
        ush8 o;
        o[0]=f2bf(v0.x); o[1]=f2bf(v0.y); o[2]=f2bf(v0.z); o[3]=f2bf(v0.w);
        o[4]=f2bf(v1.x); o[5]=f2bf(v1.y); o[6]=f2bf(v1.z); o[7]=f2bf(v1.w);
        *(ush8*)(wscat + (size_t)g * 8) = o;
    } else {
        for (int i = threadIdx.x; i < 512; i += 256)
            biascat[i] = (i < 256) ? (bsl[i] + bl[i]) : (bsr[i - 256] + br[i - 256]);
    }
}

// ---------------------------------------------------------------------------
// Kernel 0: gather embedding rows -> bf16 e2[s*64+b][d]
// ---------------------------------------------------------------------------
__global__ __launch_bounds__(256) void gather_e_kernel(
    const int* __restrict__ x, const float* __restrict__ embed_w,
    unsigned short* __restrict__ e2)
{
    const int g = blockIdx.x * 256 + threadIdx.x;  // chunk of 8 elements
    const int bs = g >> 5;                         // b*S + s
    const int b = bs >> 9, s = bs & (SS - 1);
    const int d0 = (g & 31) * 8;
    const float* src = embed_w + (size_t)x[bs] * DD + d0;
    const float4 v0 = *(const float4*)(src);
    const float4 v1 = *(const float4*)(src + 4);
    ush8 o;
    o[0]=f2bf(v0.x); o[1]=f2bf(v0.y); o[2]=f2bf(v0.z); o[3]=f2bf(v0.w);
    o[4]=f2bf(v1.x); o[5]=f2bf(v1.y); o[6]=f2bf(v1.z); o[7]=f2bf(v1.w);
    *(ush8*)(e2 + ((size_t)s * BB + b) * DD + d0) = o;
}

// ---------------------------------------------------------------------------
// Kernel 1: pre-GEMM as bf16 MFMA (swapped operands: m = e-rows of Wscat,
// n = sb-rows of e2). Output directly in the recurrence's pre2 slot layout
// (fp32, contiguous float4 per lane), biases folded.
// grid = 256 sbi * 4 mi = 1024 blocks, 256 threads.
// pre2[s][bg][ (e>>2)*64 + (b&15)*4 + (e&3) ] = e @ Ws^T + bs + b
// ---------------------------------------------------------------------------
#define PPAD 72

__global__ __launch_bounds__(256) void pre_mfma_kernel(
    const unsigned short* __restrict__ wscat,
    const unsigned short* __restrict__ e2,
    const float* __restrict__ biascat,
    float* __restrict__ pre2_l, float* __restrict__ pre2_r)
{
    __shared__ unsigned short Abuf[2][128][PPAD];
    __shared__ unsigned short Bbuf[2][128][PPAD];

    const int mi  = blockIdx.x & 3;
    const int sbi = blockIdx.x >> 2;
    const int tid = threadIdx.x;
    const int w = tid >> 6, lane = tid & 63;
    const int lr = lane & 15, g = lane >> 4;
    const int lk = g * 8;

    f32x4 acc[2][8];
#pragma unroll
    for (int mt = 0; mt < 2; ++mt)
#pragma unroll
        for (int nt = 0; nt < 8; ++nt) acc[mt][nt] = (f32x4)(0.f);

    const int strow = tid >> 3;      // 0..31
    const int skc   = (tid & 7) * 8; // 0..56

    auto stage = [&](int ks, int buf) {
        const int k0 = ks * 64;
#pragma unroll
        for (int j = 0; j < 4; ++j) {
            const int row = strow + 32 * j;
            *(bf16x8*)&Abuf[buf][row][skc] =
                *(const bf16x8*)(wscat + (size_t)(mi * 128 + row) * DD + k0 + skc);
            *(bf16x8*)&Bbuf[buf][row][skc] =
                *(const bf16x8*)(e2 + (size_t)(sbi * 128 + row) * DD + k0 + skc);
        }
    };

    stage(0, 0);
    int cur = 0;
    for (int ks = 0; ks < 4; ++ks) {
        __syncthreads();
        if (ks + 1 < 4) stage(ks + 1, cur ^ 1);
#pragma unroll
        for (int k2 = 0; k2 < 2; ++k2) {
            const int kk = k2 * 32 + lk;
            const bf16x8 a0 = *(const bf16x8*)&Abuf[cur][w * 32 + lr][kk];
            const bf16x8 a1 = *(const bf16x8*)&Abuf[cur][w * 32 + 16 + lr][kk];
#pragma unroll
            for (int nt = 0; nt < 8; ++nt) {
                const bf16x8 bv = *(const bf16x8*)&Bbuf[cur][nt * 16 + lr][kk];
                acc[0][nt] = __builtin_amdgcn_mfma_f32_16x16x32_bf16(a0, bv, acc[0][nt], 0, 0, 0);
                acc[1][nt] = __builtin_amdgcn_mfma_f32_16x16x32_bf16(a1, bv, acc[1][nt], 0, 0, 0);
            }
        }
        cur ^= 1;
    }

    // epilogue: lane holds (e = mi*128 + w*32 + mt*16 + g*4 + r, b-col = lr)
#pragma unroll
    for (int mt = 0; mt < 2; ++mt) {
        const int eg = mi * 128 + w * 32 + mt * 16 + g * 4;
        const float4 bia = *(const float4*)(biascat + eg);
        float* dstb = (eg >= 256) ? pre2_r : pre2_l;
        const int e = eg & 255;
#pragma unroll
        for (int nt = 0; nt < 8; ++nt) {
            const int sb = sbi * 128 + nt * 16 + lr;
            const int s = sb >> 6, bgq = (sb >> 4) & 3, b_loc = sb & 15;
            float4 v;
            v.x = acc[mt][nt][0] + bia.x;
            v.y = acc[mt][nt][1] + bia.y;
            v.z = acc[mt][nt][2] + bia.z;
            v.w = acc[mt][nt][3] + bia.w;
            *(float4*)(dstb + ((size_t)s * 4 + bgq) * 4096 + (e >> 2) * 64 + b_loc * 4) = v;
        }
    }
}

// ---------------------------------------------------------------------------
// Kernel 2: MFMA recurrence, BOTH directions per block for 2 waves/SIMD.
// grid = 4 blocks (batch-group of 16), 512 threads (waves 0-3: dir0,
// waves 4-7: dir1; wave wl owns e-quarter [64wl, 64wl+64)).
// Swapped operands: mfma(Wfrag, statefrag) -> D lane&15 = batch,
// rows = 4 consecutive e -> packed b64 epilogue writes.
// ---------------------------------------------------------------------------
#define CSWZ(row, off) ((off) ^ (((row) & 15) << 4))

__global__ __launch_bounds__(512, 2) void recur_mfma_kernel(
    const float* __restrict__ Wl, const float* __restrict__ Wr,
    const float* __restrict__ cl0, const float* __restrict__ cr0,
    const float* __restrict__ pre2_l, const float* __restrict__ pre2_r,
    unsigned short* __restrict__ outl, unsigned short* __restrict__ outr)
{
    __shared__ unsigned short cbf[2][2][16 * 256];  // [dir][buf][b][e] swizzled

    const int bg = blockIdx.x;
    const int b0 = bg * 16;
    const int tid  = threadIdx.x;
    const int wave = tid >> 6;
    const int dir  = wave >> 2;
    const int wl   = wave & 3;
    const int lane = tid & 63;
    const int col  = lane & 15;
    const int g    = lane >> 4;

    const float* W   = dir ? Wr : Wl;
    const float* pre = dir ? pre2_r : pre2_l;
    unsigned short* out = dir ? outr : outl;

    // stationary W as A-side fragments: wfrag[mt][ks]:
    // m=e = wl*64+mt*16+col ; k = ks*32 + g*8 + j
    bf16x8 wfrag[4][8];
#pragma unroll
    for (int mt = 0; mt < 4; ++mt)
#pragma unroll
        for (int ks = 0; ks < 8; ++ks) {
            const float* src = W + (size_t)(wl * 64 + mt * 16 + col) * DD
                                 + ks * 32 + g * 8;
            const float4 lo = *(const float4*)(src);
            const float4 hi = *(const float4*)(src + 4);
            ush8 p;
            p[0]=f2bf(lo.x); p[1]=f2bf(lo.y); p[2]=f2bf(lo.z); p[3]=f2bf(lo.w);
            p[4]=f2bf(hi.x); p[5]=f2bf(hi.y); p[6]=f2bf(hi.z); p[7]=f2bf(hi.w);
            wfrag[mt][ks] = *(bf16x8*)&p;
        }

    // init: cbf[d][0] = bf16(c0), out[:, t0] = bf16(c0)
    {
        const int d   = tid >> 8;
        const int blc = (tid >> 4) & 15;
        const int ch  = tid & 15;
        const float* c0d = d ? cr0 : cl0;
        unsigned short* outd = d ? outr : outl;
        const float* src = c0d + (size_t)(b0 + blc) * DD + ch * 16;
        const float4 v0 = *(const float4*)(src);
        const float4 v1 = *(const float4*)(src + 4);
        const float4 v2 = *(const float4*)(src + 8);
        const float4 v3 = *(const float4*)(src + 12);
        ush8 p0, p1;
        p0[0]=f2bf(v0.x); p0[1]=f2bf(v0.y); p0[2]=f2bf(v0.z); p0[3]=f2bf(v0.w);
        p0[4]=f2bf(v1.x); p0[5]=f2bf(v1.y); p0[6]=f2bf(v1.z); p0[7]=f2bf(v1.w);
        p1[0]=f2bf(v2.x); p1[1]=f2bf(v2.y); p1[2]=f2bf(v2.z); p1[3]=f2bf(v2.w);
        p1[4]=f2bf(v3.x); p1[5]=f2bf(v3.y); p1[6]=f2bf(v3.z); p1[7]=f2bf(v3.w);
        char* rowp = (char*)cbf[d][0] + blc * 512;
        *(ush8*)(rowp + CSWZ(blc, ch * 32))      = p0;
        *(ush8*)(rowp + CSWZ(blc, ch * 32 + 16)) = p1;
        const int t0 = d ? 511 : 0;
        ush8* dst = (ush8*)(outd + ((size_t)(b0 + blc) * SS + t0) * DD + ch * 16);
        dst[0] = p0; dst[1] = p1;
    }

    // pre prefetch (registers); slot base for (e = wl*64+mt*16+g*4, b = col)
    const int psl = col * 4;
    const float* pt0 = pre + ((size_t)(dir ? 511 : 0) * 4 + bg) * 4096;
    float4 pc0 = *(const float4*)(pt0 + (wl * 16 + 0 + g) * 64 + psl);
    float4 pc1 = *(const float4*)(pt0 + (wl * 16 + 4 + g) * 64 + psl);
    float4 pc2 = *(const float4*)(pt0 + (wl * 16 + 8 + g) * 64 + psl);
    float4 pc3 = *(const float4*)(pt0 + (wl * 16 + 12 + g) * 64 + psl);

    __syncthreads();

    int cur = 0;
    for (int k = 0; k < SS - 1; ++k) {
        // state B-fragments from cbf[dir][cur] (lane&15 = b, k-dim = e)
        bf16x8 sfrag[8];
        {
            const char* rowp = (const char*)cbf[dir][cur] + col * 512;
#pragma unroll
            for (int ks = 0; ks < 8; ++ks)
                sfrag[ks] = *(const bf16x8*)(rowp + CSWZ(col, ks * 64 + g * 16));
        }

        // prefetch pre for next step
        const int tnext = dir ? (SS - 2 - k) : (k + 1);
        float4 pn0, pn1, pn2, pn3;
        {
            const float* ptn = pre + ((size_t)tnext * 4 + bg) * 4096;
            pn0 = *(const float4*)(ptn + (wl * 16 + 0 + g) * 64 + psl);
            pn1 = *(const float4*)(ptn + (wl * 16 + 4 + g) * 64 + psl);
            pn2 = *(const float4*)(ptn + (wl * 16 + 8 + g) * 64 + psl);
            pn3 = *(const float4*)(ptn + (wl * 16 + 12 + g) * 64 + psl);
        }

        f32x4 acc[4];
#pragma unroll
        for (int mt = 0; mt < 4; ++mt) acc[mt] = (f32x4)(0.f);
#pragma unroll
        for (int ks = 0; ks < 8; ++ks) {
            acc[0] = __builtin_amdgcn_mfma_f32_16x16x32_bf16(wfrag[0][ks], sfrag[ks], acc[0], 0, 0, 0);
            acc[1] = __builtin_amdgcn_mfma_f32_16x16x32_bf16(wfrag[1][ks], sfrag[ks], acc[1], 0, 0, 0);
            acc[2] = __builtin_amdgcn_mfma_f32_16x16x32_bf16(wfrag[2][ks], sfrag[ks], acc[2], 0, 0, 0);
            acc[3] = __builtin_amdgcn_mfma_f32_16x16x32_bf16(wfrag[3][ks], sfrag[ks], acc[3], 0, 0, 0);
        }

        // epilogue: lane (b = col) holds 4 consecutive e per mt -> b64 writes
        {
            char* nbuf = (char*)cbf[dir][cur ^ 1] + col * 512;
#pragma unroll
            for (int mt = 0; mt < 4; ++mt) {
                const float4 pv = (mt == 0) ? pc0 : (mt == 1) ? pc1 : (mt == 2) ? pc2 : pc3;
                const float v0 = fmaxf(acc[mt][0] + pv.x, 0.f);
                const float v1 = fmaxf(acc[mt][1] + pv.y, 0.f);
                const float v2 = fmaxf(acc[mt][2] + pv.z, 0.f);
                const float v3 = fmaxf(acc[mt][3] + pv.w, 0.f);
                uint2 uu;
                uu.x = (unsigned)f2bf(v0) | ((unsigned)f2bf(v1) << 16);
                uu.y = (unsigned)f2bf(v2) | ((unsigned)f2bf(v3) << 16);
                const int eoff = (wl * 64 + mt * 16 + g * 4) * 2;
                *(uint2*)(nbuf + CSWZ(col, eoff)) = uu;
            }
        }
        pc0 = pn0; pc1 = pn1; pc2 = pn2; pc3 = pn3;

        __syncthreads();

        // coalesced out store via LDS readback
        {
            const int d   = tid >> 8;
            const int blc = (tid >> 4) & 15;
            const int ch  = tid & 15;
            unsigned short* outd = d ? outr : outl;
            const int tdst = d ? (SS - 2 - k) : (k + 1);
            const char* rowq = (const char*)cbf[d][cur ^ 1] + blc * 512;
            const ush8 p0 = *(const ush8*)(rowq + CSWZ(blc, ch * 32));
            const ush8 p1 = *(const ush8*)(rowq + CSWZ(blc, ch * 32 + 16));
            ush8* dst = (ush8*)(outd + ((size_t)(b0 + blc) * SS + tdst) * DD + ch * 16);
            dst[0] = p0; dst[1] = p1;
        }
        cur ^= 1;
    }
}

// ---------------------------------------------------------------------------
// Kernel 3: conv(1x3D) + relu + maxpool, bf16 MFMA (e-source now e2[s*64+b]).
// ---------------------------------------------------------------------------
#define KSTEP 64
#define NK 12
#define NST 4
#define APAD 72

__global__ __launch_bounds__(256) void conv_pool_kernel(
    const unsigned short* __restrict__ leftb,
    const unsigned short* __restrict__ e2,
    const unsigned short* __restrict__ rightb,
    const unsigned short* __restrict__ convwb,
    const float* __restrict__ conv_b,
    float* __restrict__ pooled)
{
    __shared__ unsigned short Abuf[2][128][APAD];
    __shared__ unsigned short Bbuf[2][128][APAD];
    __shared__ float red[4][128];

    const int b   = blockIdx.x >> 2;
    const int h0  = (blockIdx.x & 3) * 128;
    const int tid = threadIdx.x;
    const int wid = tid >> 6;
    const int lane = tid & 63;
    const int lr  = lane & 15;
    const int lk  = (lane >> 4) * 8;

    f32x4 acc[2][8];
    float pmax[8];
#pragma unroll
    for (int ht = 0; ht < 8; ++ht) {
        pmax[ht] = -INFINITY;
        acc[0][ht] = (f32x4)(0.f);
        acc[1][ht] = (f32x4)(0.f);
    }

    const int strow = tid >> 3;
    const int skc   = (tid & 7) * 8;

    auto stage = [&](int it, int buf) {
        const int stile = it / NK, kstep = it % NK;
        const int k0 = kstep * KSTEP;
        const int s0 = stile * 128;
#pragma unroll
        for (int j = 0; j < 4; ++j) {
            const int row = strow + 32 * j;
            const int ss = s0 + row;
            size_t aidx;
            const unsigned short* asrc;
            if (k0 < DD)            { asrc = leftb;  aidx = ((size_t)b * SS + ss) * DD + k0; }
            else if (k0 < 2 * DD)   { asrc = e2;     aidx = ((size_t)ss * BB + b) * DD + (k0 - DD); }
            else                    { asrc = rightb; aidx = ((size_t)b * SS + ss) * DD + (k0 - 2 * DD); }
            *(bf16x8*)&Abuf[buf][row][skc] = *(const bf16x8*)(asrc + aidx + skc);
            *(bf16x8*)&Bbuf[buf][row][skc] =
                *(const bf16x8*)(convwb + (size_t)(h0 + row) * K3D + k0 + skc);
        }
    };

    stage(0, 0);
    int cur = 0;
    for (int it = 0; it < NST * NK; ++it) {
        __syncthreads();
        if (it + 1 < NST * NK) stage(it + 1, cur ^ 1);

        const int wrow0 = wid * 32;
#pragma unroll
        for (int ks = 0; ks < 2; ++ks) {
            const int kk = ks * 32 + lk;
            const bf16x8 a0 = *(const bf16x8*)&Abuf[cur][wrow0 + lr][kk];
            const bf16x8 a1 = *(const bf16x8*)&Abuf[cur][wrow0 + 16 + lr][kk];
#pragma unroll
            for (int ht = 0; ht < 8; ++ht) {
                const bf16x8 bv = *(const bf16x8*)&Bbuf[cur][ht * 16 + lr][kk];
                acc[0][ht] = __builtin_amdgcn_mfma_f32_16x16x32_bf16(a0, bv, acc[0][ht], 0, 0, 0);
                acc[1][ht] = __builtin_amdgcn_mfma_f32_16x16x32_bf16(a1, bv, acc[1][ht], 0, 0, 0);
            }
        }
        if ((it % NK) == NK - 1) {
#pragma unroll
            for (int st = 0; st < 2; ++st)
#pragma unroll
                for (int ht = 0; ht < 8; ++ht) {
#pragma unroll
                    for (int r = 0; r < 4; ++r)
                        pmax[ht] = fmaxf(pmax[ht], acc[st][ht][r]);
                    acc[st][ht] = (f32x4)(0.f);
                }
        }
        cur ^= 1;
    }

#pragma unroll
    for (int ht = 0; ht < 8; ++ht) {
        float m = pmax[ht];
        m = fmaxf(m, __shfl_xor(m, 16));
        m = fmaxf(m, __shfl_xor(m, 32));
        if (lane < 16) red[wid][ht * 16 + lane] = m;
    }
    __syncthreads();
    if (tid < 128) {
        const float m = fmaxf(fmaxf(red[0][tid], red[1][tid]),
                              fmaxf(red[2][tid], red[3][tid]));
        pooled[(size_t)b * HH + h0 + tid] = fmaxf(m + conv_b[h0 + tid], 0.f);
    }
}

// ---------------------------------------------------------------------------
// Kernel 4: final FC (unchanged).
// ---------------------------------------------------------------------------
__global__ void fc_kernel(const float* __restrict__ pooled,
                          const float* __restrict__ fc_w,
                          const float* __restrict__ fc_b,
                          float* __restrict__ out)
{
    const int t = threadIdx.x;
    if (t >= BB * NCLS) return;
    const int b = t / NCLS, c = t % NCLS;
    float acc = fc_b[c];
    for (int h = 0; h < HH; ++h)
        acc += pooled[(size_t)b * HH + h] * fc_w[(size_t)c * HH + h];
    out[b * NCLS + c] = acc;
}

// ---------------------------------------------------------------------------
extern "C" void kernel_launch(void* const* d_in, const int* in_sizes, int n_in,
                              void* d_out, int out_size, void* d_ws, size_t ws_size,
                              hipStream_t stream)
{
    const int*   x       = (const int*)  d_in[0];
    const float* embed_w = (const float*)d_in[1];
    const float* Wl      = (const float*)d_in[2];
    const float* bl      = (const float*)d_in[3];
    const float* Wsl     = (const float*)d_in[4];
    const float* bsl     = (const float*)d_in[5];
    const float* Wr      = (const float*)d_in[6];
    const float* br      = (const float*)d_in[7];
    const float* Wsr     = (const float*)d_in[8];
    const float* bsr     = (const float*)d_in[9];
    const float* conv_w  = (const float*)d_in[10];
    const float* conv_b  = (const float*)d_in[11];
    const float* fc_w    = (const float*)d_in[12];
    const float* fc_b    = (const float*)d_in[13];
    const float* cl0     = (const float*)d_in[14];
    const float* cr0     = (const float*)d_in[15];
    float* out = (float*)d_out;

    char* ws = (char*)d_ws;
    const size_t SZf = (size_t)SS * BB * DD * sizeof(float);           // 33.55 MB
    const size_t SZh = (size_t)SS * BB * DD * sizeof(unsigned short);  // 16.78 MB
    float*          pre2_l = (float*)(ws);
    float*          pre2_r = (float*)(ws + SZf);
    unsigned short* leftb  = (unsigned short*)(ws + 2 * SZf);
    unsigned short* rightb = (unsigned short*)(ws + 2 * SZf + SZh);
    unsigned short* e2     = (unsigned short*)(ws + 2 * SZf + 2 * SZh);
    unsigned short* convwb = (unsigned short*)(ws + 2 * SZf + 3 * SZh);
    unsigned short* wscat  = (unsigned short*)(ws + 2 * SZf + 3 * SZh + (size_t)HH * K3D * 2);
    float*          biascat= (float*)(ws + 2 * SZf + 3 * SZh + (size_t)HH * K3D * 2 + (size_t)512 * DD * 2);
    float*          pooled = (float*)(ws + 2 * SZf + 3 * SZh + (size_t)HH * K3D * 2 + (size_t)512 * DD * 2 + 2048);

    prep_kernel<<<257, 256, 0, stream>>>(conv_w, Wsl, Wsr, bsl, bl, bsr, br,
                                         convwb, wscat, biascat);

    gather_e_kernel<<<(BB * SS * DD / 8) / 256, 256, 0, stream>>>(x, embed_w, e2);

    pre_mfma_kernel<<<1024, 256, 0, stream>>>(wscat, e2, biascat, pre2_l, pre2_r);

    recur_mfma_kernel<<<4, 512, 0, stream>>>(
        Wl, Wr, cl0, cr0, pre2_l, pre2_r, leftb, rightb);

    conv_pool_kernel<<<BB * (HH / 128), 256, 0, stream>>>(
        leftb, e2, rightb, convwb, conv_b, pooled);

    fc_kernel<<<1, BB * NCLS, 0, stream>>>(pooled, fc_w, fc_b, out);
}

// Round 6
// 495.689 us; speedup vs baseline: 1.3647x; 1.3647x over previous
//
#include <hip/hip_runtime.h>
#include <hip/hip_bf16.h>

#define VOCAB 50000
#define DD 256
#define NCLS 10
#define BB 64
#define SS 512
#define HH 512
#define K3D 768

typedef __attribute__((ext_vector_type(8))) short bf16x8;
typedef __attribute__((ext_vector_type(8))) unsigned short ush8;
typedef __attribute__((ext_vector_type(4))) float f32x4;

static __device__ __forceinline__ unsigned short f2bf(float f) {
    __hip_bfloat16 h = __float2bfloat16(f);
    return *reinterpret_cast<unsigned short*>(&h);
}

// ---------------------------------------------------------------------------
// Kernel P: prep — convert conv_w, build Wscat (bf16 concat Wsl|Wsr), biascat.
// ---------------------------------------------------------------------------
__global__ __launch_bounds__(256) void prep_kernel(
    const float* __restrict__ conv_w,
    const float* __restrict__ Wsl, const float* __restrict__ Wsr,
    const float* __restrict__ bsl, const float* __restrict__ bl,
    const float* __restrict__ bsr, const float* __restrict__ br,
    unsigned short* __restrict__ convwb,
    unsigned short* __restrict__ wscat,
    float* __restrict__ biascat)
{
    const int bid = blockIdx.x;
    if (bid < 192) {
        const int g = bid * 256 + threadIdx.x;
        const float* src = conv_w + (size_t)g * 8;
        const float4 v0 = *(const float4*)(src);
        const float4 v1 = *(const float4*)(src + 4);
        ush8 o;
        o[0]=f2bf(v0.x); o[1]=f2bf(v0.y); o[2]=f2bf(v0.z); o[3]=f2bf(v0.w);
        o[4]=f2bf(v1.x); o[5]=f2bf(v1.y); o[6]=f2bf(v1.z); o[7]=f2bf(v1.w);
        *(ush8*)(convwb + (size_t)g * 8) = o;
    } else if (bid < 256) {
        const int g = (bid - 192) * 256 + threadIdx.x;
        const int row = g >> 5, d0 = (g & 31) * 8;
        const float* src = (row < 256 ? Wsl + (size_t)row * DD
                                      : Wsr + (size_t)(row - 256) * DD) + d0;
        const float4 v0 = *(const float4*)(src);
        const float4 v1 = *(const float4*)(src + 4);
        ush8 o;
        o[0]=f2bf(v0.x); o[1]=f2bf(v0.y); o[2]=f2bf(v0.z); o[3]=f2bf(v0.w);
        o[4]=f2bf(v1.x); o[5]=f2bf(v1.y); o[6]=f2bf(v1.z); o[7]=f2bf(v1.w);
        *(ush8*)(wscat + (size_t)g * 8) = o;
    } else {
        for (int i = threadIdx.x; i < 512; i += 256)
            biascat[i] = (i < 256) ? (bsl[i] + bl[i]) : (bsr[i - 256] + br[i - 256]);
    }
}

// ---------------------------------------------------------------------------
// Kernel 0: gather embedding rows -> bf16 e2[s*64+b][d]
// ---------------------------------------------------------------------------
__global__ __launch_bounds__(256) void gather_e_kernel(
    const int* __restrict__ x, const float* __restrict__ embed_w,
    unsigned short* __restrict__ e2)
{
    const int g = blockIdx.x * 256 + threadIdx.x;
    const int bs = g >> 5;                         // b*S + s
    const int b = bs >> 9, s = bs & (SS - 1);
    const int d0 = (g & 31) * 8;
    const float* src = embed_w + (size_t)x[bs] * DD + d0;
    const float4 v0 = *(const float4*)(src);
    const float4 v1 = *(const float4*)(src + 4);
    ush8 o;
    o[0]=f2bf(v0.x); o[1]=f2bf(v0.y); o[2]=f2bf(v0.z); o[3]=f2bf(v0.w);
    o[4]=f2bf(v1.x); o[5]=f2bf(v1.y); o[6]=f2bf(v1.z); o[7]=f2bf(v1.w);
    *(ush8*)(e2 + ((size_t)s * BB + b) * DD + d0) = o;
}

// ---------------------------------------------------------------------------
// Kernel 1: pre-GEMM as bf16 MFMA. Output in the recurrence's pre2 slot
// layout (fp32), biases folded. grid = 1024 blocks, 256 threads.
// ---------------------------------------------------------------------------
#define PPAD 72

__global__ __launch_bounds__(256) void pre_mfma_kernel(
    const unsigned short* __restrict__ wscat,
    const unsigned short* __restrict__ e2,
    const float* __restrict__ biascat,
    float* __restrict__ pre2_l, float* __restrict__ pre2_r)
{
    __shared__ unsigned short Abuf[2][128][PPAD];
    __shared__ unsigned short Bbuf[2][128][PPAD];

    const int mi  = blockIdx.x & 3;
    const int sbi = blockIdx.x >> 2;
    const int tid = threadIdx.x;
    const int w = tid >> 6, lane = tid & 63;
    const int lr = lane & 15, g = lane >> 4;
    const int lk = g * 8;

    f32x4 acc[2][8];
#pragma unroll
    for (int mt = 0; mt < 2; ++mt)
#pragma unroll
        for (int nt = 0; nt < 8; ++nt) acc[mt][nt] = (f32x4)(0.f);

    const int strow = tid >> 3;
    const int skc   = (tid & 7) * 8;

    auto stage = [&](int ks, int buf) {
        const int k0 = ks * 64;
#pragma unroll
        for (int j = 0; j < 4; ++j) {
            const int row = strow + 32 * j;
            *(bf16x8*)&Abuf[buf][row][skc] =
                *(const bf16x8*)(wscat + (size_t)(mi * 128 + row) * DD + k0 + skc);
            *(bf16x8*)&Bbuf[buf][row][skc] =
                *(const bf16x8*)(e2 + (size_t)(sbi * 128 + row) * DD + k0 + skc);
        }
    };

    stage(0, 0);
    int cur = 0;
    for (int ks = 0; ks < 4; ++ks) {
        __syncthreads();
        if (ks + 1 < 4) stage(ks + 1, cur ^ 1);
#pragma unroll
        for (int k2 = 0; k2 < 2; ++k2) {
            const int kk = k2 * 32 + lk;
            const bf16x8 a0 = *(const bf16x8*)&Abuf[cur][w * 32 + lr][kk];
            const bf16x8 a1 = *(const bf16x8*)&Abuf[cur][w * 32 + 16 + lr][kk];
#pragma unroll
            for (int nt = 0; nt < 8; ++nt) {
                const bf16x8 bv = *(const bf16x8*)&Bbuf[cur][nt * 16 + lr][kk];
                acc[0][nt] = __builtin_amdgcn_mfma_f32_16x16x32_bf16(a0, bv, acc[0][nt], 0, 0, 0);
                acc[1][nt] = __builtin_amdgcn_mfma_f32_16x16x32_bf16(a1, bv, acc[1][nt], 0, 0, 0);
            }
        }
        cur ^= 1;
    }

#pragma unroll
    for (int mt = 0; mt < 2; ++mt) {
        const int eg = mi * 128 + w * 32 + mt * 16 + g * 4;
        const float4 bia = *(const float4*)(biascat + eg);
        float* dstb = (eg >= 256) ? pre2_r : pre2_l;
        const int e = eg & 255;
#pragma unroll
        for (int nt = 0; nt < 8; ++nt) {
            const int sb = sbi * 128 + nt * 16 + lr;
            const int s = sb >> 6, bgq = (sb >> 4) & 3, b_loc = sb & 15;
            float4 v;
            v.x = acc[mt][nt][0] + bia.x;
            v.y = acc[mt][nt][1] + bia.y;
            v.z = acc[mt][nt][2] + bia.z;
            v.w = acc[mt][nt][3] + bia.w;
            *(float4*)(dstb + ((size_t)s * 4 + bgq) * 4096 + (e >> 2) * 64 + b_loc * 4) = v;
        }
    }
}

// ---------------------------------------------------------------------------
// Kernel 2: MFMA recurrence. 8 blocks (dir*4 + bg), 256 thr (4 waves).
// Raw s_barrier (lgkm-only drain) so pre global loads stay in flight across
// steps; 2-step-deep register prefetch of pre; direct reg->global out stores
// into out[t][b][e] layout.
// ---------------------------------------------------------------------------
#define CSWZ(row, off) ((off) ^ (((row) & 15) << 4))

__global__ __launch_bounds__(256, 1) void recur_mfma_kernel(
    const float* __restrict__ Wl, const float* __restrict__ Wr,
    const float* __restrict__ cl0, const float* __restrict__ cr0,
    const float* __restrict__ pre2_l, const float* __restrict__ pre2_r,
    unsigned short* __restrict__ outl, unsigned short* __restrict__ outr)
{
    __shared__ unsigned short cbf[2][16 * 256];  // [buf][b][e] swizzled rows

    const int dir = blockIdx.x >> 2;
    const int bg  = blockIdx.x & 3;
    const int b0  = bg * 16;
    const int tid  = threadIdx.x;
    const int wl   = tid >> 6;
    const int lane = tid & 63;
    const int col  = lane & 15;   // batch row
    const int g    = lane >> 4;

    const float* W   = dir ? Wr : Wl;
    const float* c0  = dir ? cr0 : cl0;
    const float* pre = dir ? pre2_r : pre2_l;
    unsigned short* out = dir ? outr : outl;

    // stationary W as A-side fragments: m=e = wl*64+mt*16+col ; k = ks*32+g*8+j
    bf16x8 wfrag[4][8];
#pragma unroll
    for (int mt = 0; mt < 4; ++mt)
#pragma unroll
        for (int ks = 0; ks < 8; ++ks) {
            const float* src = W + (size_t)(wl * 64 + mt * 16 + col) * DD
                                 + ks * 32 + g * 8;
            const float4 lo = *(const float4*)(src);
            const float4 hi = *(const float4*)(src + 4);
            ush8 p;
            p[0]=f2bf(lo.x); p[1]=f2bf(lo.y); p[2]=f2bf(lo.z); p[3]=f2bf(lo.w);
            p[4]=f2bf(hi.x); p[5]=f2bf(hi.y); p[6]=f2bf(hi.z); p[7]=f2bf(hi.w);
            wfrag[mt][ks] = *(bf16x8*)&p;
        }

    // init: cbf[0] = bf16(c0), out[t0] = bf16(c0)
    {
        const int blc = tid >> 4;
        const int ch  = tid & 15;
        const float* src = c0 + (size_t)(b0 + blc) * DD + ch * 16;
        const float4 v0 = *(const float4*)(src);
        const float4 v1 = *(const float4*)(src + 4);
        const float4 v2 = *(const float4*)(src + 8);
        const float4 v3 = *(const float4*)(src + 12);
        ush8 p0, p1;
        p0[0]=f2bf(v0.x); p0[1]=f2bf(v0.y); p0[2]=f2bf(v0.z); p0[3]=f2bf(v0.w);
        p0[4]=f2bf(v1.x); p0[5]=f2bf(v1.y); p0[6]=f2bf(v1.z); p0[7]=f2bf(v1.w);
        p1[0]=f2bf(v2.x); p1[1]=f2bf(v2.y); p1[2]=f2bf(v2.z); p1[3]=f2bf(v2.w);
        p1[4]=f2bf(v3.x); p1[5]=f2bf(v3.y); p1[6]=f2bf(v3.z); p1[7]=f2bf(v3.w);
        char* rowp = (char*)cbf[0] + blc * 512;
        *(ush8*)(rowp + CSWZ(blc, ch * 32))      = p0;
        *(ush8*)(rowp + CSWZ(blc, ch * 32 + 16)) = p1;
        const int t0 = dir ? 511 : 0;
        ush8* dst = (ush8*)(out + ((size_t)t0 * BB + b0 + blc) * DD + ch * 16);
        dst[0] = p0; dst[1] = p1;
    }

    // pre prefetch, 2 steps deep (named regs, static)
    const int psl = col * 4;
#define PREPTR(kk) (pre + ((size_t)(dir ? (511 - (kk)) : (kk)) * 4 + bg) * 4096)
    const float* pp0 = PREPTR(0);
    float4 pA0 = *(const float4*)(pp0 + (wl * 16 + 0  + g) * 64 + psl);
    float4 pA1 = *(const float4*)(pp0 + (wl * 16 + 4  + g) * 64 + psl);
    float4 pA2 = *(const float4*)(pp0 + (wl * 16 + 8  + g) * 64 + psl);
    float4 pA3 = *(const float4*)(pp0 + (wl * 16 + 12 + g) * 64 + psl);
    const float* pp1 = PREPTR(1);
    float4 pB0 = *(const float4*)(pp1 + (wl * 16 + 0  + g) * 64 + psl);
    float4 pB1 = *(const float4*)(pp1 + (wl * 16 + 4  + g) * 64 + psl);
    float4 pB2 = *(const float4*)(pp1 + (wl * 16 + 8  + g) * 64 + psl);
    float4 pB3 = *(const float4*)(pp1 + (wl * 16 + 12 + g) * 64 + psl);

    __syncthreads();

    int cur = 0;
    for (int k = 0; k < SS - 1; ++k) {
        // state B-fragments from cbf[cur] (lane&15 = b, k-dim = e)
        bf16x8 sfrag[8];
        {
            const char* rowp = (const char*)cbf[cur] + col * 512;
#pragma unroll
            for (int ks = 0; ks < 8; ++ks)
                sfrag[ks] = *(const bf16x8*)(rowp + CSWZ(col, ks * 64 + g * 16));
        }

        // issue pre loads for step k+2 (stay in flight across the barrier)
        const int kpre = (k + 2 <= SS - 2) ? (k + 2) : (SS - 2);
        const float* pn = PREPTR(kpre);
        const float4 pN0 = *(const float4*)(pn + (wl * 16 + 0  + g) * 64 + psl);
        const float4 pN1 = *(const float4*)(pn + (wl * 16 + 4  + g) * 64 + psl);
        const float4 pN2 = *(const float4*)(pn + (wl * 16 + 8  + g) * 64 + psl);
        const float4 pN3 = *(const float4*)(pn + (wl * 16 + 12 + g) * 64 + psl);

        f32x4 acc[4];
#pragma unroll
        for (int mt = 0; mt < 4; ++mt) acc[mt] = (f32x4)(0.f);
#pragma unroll
        for (int ks = 0; ks < 8; ++ks) {
            acc[0] = __builtin_amdgcn_mfma_f32_16x16x32_bf16(wfrag[0][ks], sfrag[ks], acc[0], 0, 0, 0);
            acc[1] = __builtin_amdgcn_mfma_f32_16x16x32_bf16(wfrag[1][ks], sfrag[ks], acc[1], 0, 0, 0);
            acc[2] = __builtin_amdgcn_mfma_f32_16x16x32_bf16(wfrag[2][ks], sfrag[ks], acc[2], 0, 0, 0);
            acc[3] = __builtin_amdgcn_mfma_f32_16x16x32_bf16(wfrag[3][ks], sfrag[ks], acc[3], 0, 0, 0);
        }

        // epilogue: relu(acc + pre) -> LDS (next state) + direct global store
        const int tdst = dir ? (SS - 2 - k) : (k + 1);
        {
            char* nbuf = (char*)cbf[cur ^ 1] + col * 512;
            unsigned short* outrow = out + ((size_t)tdst * BB + b0 + col) * DD;
#pragma unroll
            for (int mt = 0; mt < 4; ++mt) {
                const float4 pv = (mt == 0) ? pA0 : (mt == 1) ? pA1 : (mt == 2) ? pA2 : pA3;
                const float v0 = fmaxf(acc[mt][0] + pv.x, 0.f);
                const float v1 = fmaxf(acc[mt][1] + pv.y, 0.f);
                const float v2 = fmaxf(acc[mt][2] + pv.z, 0.f);
                const float v3 = fmaxf(acc[mt][3] + pv.w, 0.f);
                uint2 uu;
                uu.x = (unsigned)f2bf(v0) | ((unsigned)f2bf(v1) << 16);
                uu.y = (unsigned)f2bf(v2) | ((unsigned)f2bf(v3) << 16);
                const int eoff = (wl * 64 + mt * 16 + g * 4) * 2;
                *(uint2*)(nbuf + CSWZ(col, eoff)) = uu;
                *(uint2*)(outrow + wl * 64 + mt * 16 + g * 4) = uu;
            }
        }
        pA0 = pB0; pA1 = pB1; pA2 = pB2; pA3 = pB3;
        pB0 = pN0; pB1 = pN1; pB2 = pN2; pB3 = pN3;

        // raw barrier: drain LDS writes only; global loads stay in flight
        asm volatile("s_waitcnt lgkmcnt(0)" ::: "memory");
        __builtin_amdgcn_s_barrier();
        asm volatile("" ::: "memory");
        cur ^= 1;
    }
#undef PREPTR
}

// ---------------------------------------------------------------------------
// Kernel 3: conv(1x3D) + relu + maxpool, bf16 MFMA.
// left/right now in [t][b][e] layout (same indexing form as e2).
// ---------------------------------------------------------------------------
#define KSTEP 64
#define NK 12
#define NST 4
#define APAD 72

__global__ __launch_bounds__(256) void conv_pool_kernel(
    const unsigned short* __restrict__ leftb,
    const unsigned short* __restrict__ e2,
    const unsigned short* __restrict__ rightb,
    const unsigned short* __restrict__ convwb,
    const float* __restrict__ conv_b,
    float* __restrict__ pooled)
{
    __shared__ unsigned short Abuf[2][128][APAD];
    __shared__ unsigned short Bbuf[2][128][APAD];
    __shared__ float red[4][128];

    const int b   = blockIdx.x >> 2;
    const int h0  = (blockIdx.x & 3) * 128;
    const int tid = threadIdx.x;
    const int wid = tid >> 6;
    const int lane = tid & 63;
    const int lr  = lane & 15;
    const int lk  = (lane >> 4) * 8;

    f32x4 acc[2][8];
    float pmax[8];
#pragma unroll
    for (int ht = 0; ht < 8; ++ht) {
        pmax[ht] = -INFINITY;
        acc[0][ht] = (f32x4)(0.f);
        acc[1][ht] = (f32x4)(0.f);
    }

    const int strow = tid >> 3;
    const int skc   = (tid & 7) * 8;

    auto stage = [&](int it, int buf) {
        const int stile = it / NK, kstep = it % NK;
        const int k0 = kstep * KSTEP;
        const int s0 = stile * 128;
        const unsigned short* asrc;
        int koff;
        if (k0 < DD)          { asrc = leftb;  koff = k0; }
        else if (k0 < 2 * DD) { asrc = e2;     koff = k0 - DD; }
        else                  { asrc = rightb; koff = k0 - 2 * DD; }
#pragma unroll
        for (int j = 0; j < 4; ++j) {
            const int row = strow + 32 * j;
            const int ss = s0 + row;
            *(bf16x8*)&Abuf[buf][row][skc] =
                *(const bf16x8*)(asrc + ((size_t)ss * BB + b) * DD + koff + skc);
            *(bf16x8*)&Bbuf[buf][row][skc] =
                *(const bf16x8*)(convwb + (size_t)(h0 + row) * K3D + k0 + skc);
        }
    };

    stage(0, 0);
    int cur = 0;
    for (int it = 0; it < NST * NK; ++it) {
        __syncthreads();
        if (it + 1 < NST * NK) stage(it + 1, cur ^ 1);

        const int wrow0 = wid * 32;
#pragma unroll
        for (int ks = 0; ks < 2; ++ks) {
            const int kk = ks * 32 + lk;
            const bf16x8 a0 = *(const bf16x8*)&Abuf[cur][wrow0 + lr][kk];
            const bf16x8 a1 = *(const bf16x8*)&Abuf[cur][wrow0 + 16 + lr][kk];
#pragma unroll
            for (int ht = 0; ht < 8; ++ht) {
                const bf16x8 bv = *(const bf16x8*)&Bbuf[cur][ht * 16 + lr][kk];
                acc[0][ht] = __builtin_amdgcn_mfma_f32_16x16x32_bf16(a0, bv, acc[0][ht], 0, 0, 0);
                acc[1][ht] = __builtin_amdgcn_mfma_f32_16x16x32_bf16(a1, bv, acc[1][ht], 0, 0, 0);
            }
        }
        if ((it % NK) == NK - 1) {
#pragma unroll
            for (int st = 0; st < 2; ++st)
#pragma unroll
                for (int ht = 0; ht < 8; ++ht) {
#pragma unroll
                    for (int r = 0; r < 4; ++r)
                        pmax[ht] = fmaxf(pmax[ht], acc[st][ht][r]);
                    acc[st][ht] = (f32x4)(0.f);
                }
        }
        cur ^= 1;
    }

#pragma unroll
    for (int ht = 0; ht < 8; ++ht) {
        float m = pmax[ht];
        m = fmaxf(m, __shfl_xor(m, 16));
        m = fmaxf(m, __shfl_xor(m, 32));
        if (lane < 16) red[wid][ht * 16 + lane] = m;
    }
    __syncthreads();
    if (tid < 128) {
        const float m = fmaxf(fmaxf(red[0][tid], red[1][tid]),
                              fmaxf(red[2][tid], red[3][tid]));
        pooled[(size_t)b * HH + h0 + tid] = fmaxf(m + conv_b[h0 + tid], 0.f);
    }
}

// ---------------------------------------------------------------------------
// Kernel 4: final FC (unchanged).
// ---------------------------------------------------------------------------
__global__ void fc_kernel(const float* __restrict__ pooled,
                          const float* __restrict__ fc_w,
                          const float* __restrict__ fc_b,
                          float* __restrict__ out)
{
    const int t = threadIdx.x;
    if (t >= BB * NCLS) return;
    const int b = t / NCLS, c = t % NCLS;
    float acc = fc_b[c];
    for (int h = 0; h < HH; ++h)
        acc += pooled[(size_t)b * HH + h] * fc_w[(size_t)c * HH + h];
    out[b * NCLS + c] = acc;
}

// ---------------------------------------------------------------------------
extern "C" void kernel_launch(void* const* d_in, const int* in_sizes, int n_in,
                              void* d_out, int out_size, void* d_ws, size_t ws_size,
                              hipStream_t stream)
{
    const int*   x       = (const int*)  d_in[0];
    const float* embed_w = (const float*)d_in[1];
    const float* Wl      = (const float*)d_in[2];
    const float* bl      = (const float*)d_in[3];
    const float* Wsl     = (const float*)d_in[4];
    const float* bsl     = (const float*)d_in[5];
    const float* Wr      = (const float*)d_in[6];
    const float* br      = (const float*)d_in[7];
    const float* Wsr     = (const float*)d_in[8];
    const float* bsr     = (const float*)d_in[9];
    const float* conv_w  = (const float*)d_in[10];
    const float* conv_b  = (const float*)d_in[11];
    const float* fc_w    = (const float*)d_in[12];
    const float* fc_b    = (const float*)d_in[13];
    const float* cl0     = (const float*)d_in[14];
    const float* cr0     = (const float*)d_in[15];
    float* out = (float*)d_out;

    char* ws = (char*)d_ws;
    const size_t SZf = (size_t)SS * BB * DD * sizeof(float);           // 33.55 MB
    const size_t SZh = (size_t)SS * BB * DD * sizeof(unsigned short);  // 16.78 MB
    float*          pre2_l = (float*)(ws);
    float*          pre2_r = (float*)(ws + SZf);
    unsigned short* leftb  = (unsigned short*)(ws + 2 * SZf);
    unsigned short* rightb = (unsigned short*)(ws + 2 * SZf + SZh);
    unsigned short* e2     = (unsigned short*)(ws + 2 * SZf + 2 * SZh);
    unsigned short* convwb = (unsigned short*)(ws + 2 * SZf + 3 * SZh);
    unsigned short* wscat  = (unsigned short*)(ws + 2 * SZf + 3 * SZh + (size_t)HH * K3D * 2);
    float*          biascat= (float*)(ws + 2 * SZf + 3 * SZh + (size_t)HH * K3D * 2 + (size_t)512 * DD * 2);
    float*          pooled = (float*)(ws + 2 * SZf + 3 * SZh + (size_t)HH * K3D * 2 + (size_t)512 * DD * 2 + 2048);

    prep_kernel<<<257, 256, 0, stream>>>(conv_w, Wsl, Wsr, bsl, bl, bsr, br,
                                         convwb, wscat, biascat);

    gather_e_kernel<<<(BB * SS * DD / 8) / 256, 256, 0, stream>>>(x, embed_w, e2);

    pre_mfma_kernel<<<1024, 256, 0, stream>>>(wscat, e2, biascat, pre2_l, pre2_r);

    recur_mfma_kernel<<<8, 256, 0, stream>>>(
        Wl, Wr, cl0, cr0, pre2_l, pre2_r, leftb, rightb);

    conv_pool_kernel<<<BB * (HH / 128), 256, 0, stream>>>(
        leftb, e2, rightb, convwb, conv_b, pooled);

    fc_kernel<<<1, BB * NCLS, 0, stream>>>(pooled, fc_w, fc_b, out);
}

// Round 7
// 474.498 us; speedup vs baseline: 1.4257x; 1.0447x over previous
//
#include <hip/hip_runtime.h>
#include <hip/hip_bf16.h>

#define VOCAB 50000
#define DD 256
#define NCLS 10
#define BB 64
#define SS 512
#define HH 512
#define K3D 768

typedef __attribute__((ext_vector_type(8))) short bf16x8;
typedef __attribute__((ext_vector_type(8))) unsigned short ush8;
typedef __attribute__((ext_vector_type(4))) float f32x4;

static __device__ __forceinline__ unsigned short f2bf(float f) {
    __hip_bfloat16 h = __float2bfloat16(f);
    return *reinterpret_cast<unsigned short*>(&h);
}

// ---------------------------------------------------------------------------
// Kernel P: prep — convert conv_w, build Wscat (bf16 concat Wsl|Wsr), biascat.
// ---------------------------------------------------------------------------
__global__ __launch_bounds__(256) void prep_kernel(
    const float* __restrict__ conv_w,
    const float* __restrict__ Wsl, const float* __restrict__ Wsr,
    const float* __restrict__ bsl, const float* __restrict__ bl,
    const float* __restrict__ bsr, const float* __restrict__ br,
    unsigned short* __restrict__ convwb,
    unsigned short* __restrict__ wscat,
    float* __restrict__ biascat)
{
    const int bid = blockIdx.x;
    if (bid < 192) {
        const int g = bid * 256 + threadIdx.x;
        const float* src = conv_w + (size_t)g * 8;
        const float4 v0 = *(const float4*)(src);
        const float4 v1 = *(const float4*)(src + 4);
        ush8 o;
        o[0]=f2bf(v0.x); o[1]=f2bf(v0.y); o[2]=f2bf(v0.z); o[3]=f2bf(v0.w);
        o[4]=f2bf(v1.x); o[5]=f2bf(v1.y); o[6]=f2bf(v1.z); o[7]=f2bf(v1.w);
        *(ush8*)(convwb + (size_t)g * 8) = o;
    } else if (bid < 256) {
        const int g = (bid - 192) * 256 + threadIdx.x;
        const int row = g >> 5, d0 = (g & 31) * 8;
        const float* src = (row < 256 ? Wsl + (size_t)row * DD
                                      : Wsr + (size_t)(row - 256) * DD) + d0;
        const float4 v0 = *(const float4*)(src);
        const float4 v1 = *(const float4*)(src + 4);
        ush8 o;
        o[0]=f2bf(v0.x); o[1]=f2bf(v0.y); o[2]=f2bf(v0.z); o[3]=f2bf(v0.w);
        o[4]=f2bf(v1.x); o[5]=f2bf(v1.y); o[6]=f2bf(v1.z); o[7]=f2bf(v1.w);
        *(ush8*)(wscat + (size_t)g * 8) = o;
    } else {
        for (int i = threadIdx.x; i < 512; i += 256)
            biascat[i] = (i < 256) ? (bsl[i] + bl[i]) : (bsr[i - 256] + br[i - 256]);
    }
}

// ---------------------------------------------------------------------------
// Kernel 0: gather embedding rows -> bf16 e2[s*64+b][d]
// ---------------------------------------------------------------------------
__global__ __launch_bounds__(256) void gather_e_kernel(
    const int* __restrict__ x, const float* __restrict__ embed_w,
    unsigned short* __restrict__ e2)
{
    const int g = blockIdx.x * 256 + threadIdx.x;
    const int bs = g >> 5;                         // b*S + s
    const int b = bs >> 9, s = bs & (SS - 1);
    const int d0 = (g & 31) * 8;
    const float* src = embed_w + (size_t)x[bs] * DD + d0;
    const float4 v0 = *(const float4*)(src);
    const float4 v1 = *(const float4*)(src + 4);
    ush8 o;
    o[0]=f2bf(v0.x); o[1]=f2bf(v0.y); o[2]=f2bf(v0.z); o[3]=f2bf(v0.w);
    o[4]=f2bf(v1.x); o[5]=f2bf(v1.y); o[6]=f2bf(v1.z); o[7]=f2bf(v1.w);
    *(ush8*)(e2 + ((size_t)s * BB + b) * DD + d0) = o;
}

// ---------------------------------------------------------------------------
// Kernel 1: pre-GEMM as bf16 MFMA. Output in the recurrence's pre2 slot
// layout (fp32), biases folded. grid = 1024 blocks, 256 threads.
// ---------------------------------------------------------------------------
#define PPAD 72

__global__ __launch_bounds__(256) void pre_mfma_kernel(
    const unsigned short* __restrict__ wscat,
    const unsigned short* __restrict__ e2,
    const float* __restrict__ biascat,
    float* __restrict__ pre2_l, float* __restrict__ pre2_r)
{
    __shared__ unsigned short Abuf[2][128][PPAD];
    __shared__ unsigned short Bbuf[2][128][PPAD];

    const int mi  = blockIdx.x & 3;
    const int sbi = blockIdx.x >> 2;
    const int tid = threadIdx.x;
    const int w = tid >> 6, lane = tid & 63;
    const int lr = lane & 15, g = lane >> 4;
    const int lk = g * 8;

    f32x4 acc[2][8];
#pragma unroll
    for (int mt = 0; mt < 2; ++mt)
#pragma unroll
        for (int nt = 0; nt < 8; ++nt) acc[mt][nt] = (f32x4)(0.f);

    const int strow = tid >> 3;
    const int skc   = (tid & 7) * 8;

    auto stage = [&](int ks, int buf) {
        const int k0 = ks * 64;
#pragma unroll
        for (int j = 0; j < 4; ++j) {
            const int row = strow + 32 * j;
            *(bf16x8*)&Abuf[buf][row][skc] =
                *(const bf16x8*)(wscat + (size_t)(mi * 128 + row) * DD + k0 + skc);
            *(bf16x8*)&Bbuf[buf][row][skc] =
                *(const bf16x8*)(e2 + (size_t)(sbi * 128 + row) * DD + k0 + skc);
        }
    };

    stage(0, 0);
    int cur = 0;
    for (int ks = 0; ks < 4; ++ks) {
        __syncthreads();
        if (ks + 1 < 4) stage(ks + 1, cur ^ 1);
#pragma unroll
        for (int k2 = 0; k2 < 2; ++k2) {
            const int kk = k2 * 32 + lk;
            const bf16x8 a0 = *(const bf16x8*)&Abuf[cur][w * 32 + lr][kk];
            const bf16x8 a1 = *(const bf16x8*)&Abuf[cur][w * 32 + 16 + lr][kk];
#pragma unroll
            for (int nt = 0; nt < 8; ++nt) {
                const bf16x8 bv = *(const bf16x8*)&Bbuf[cur][nt * 16 + lr][kk];
                acc[0][nt] = __builtin_amdgcn_mfma_f32_16x16x32_bf16(a0, bv, acc[0][nt], 0, 0, 0);
                acc[1][nt] = __builtin_amdgcn_mfma_f32_16x16x32_bf16(a1, bv, acc[1][nt], 0, 0, 0);
            }
        }
        cur ^= 1;
    }

#pragma unroll
    for (int mt = 0; mt < 2; ++mt) {
        const int eg = mi * 128 + w * 32 + mt * 16 + g * 4;
        const float4 bia = *(const float4*)(biascat + eg);
        float* dstb = (eg >= 256) ? pre2_r : pre2_l;
        const int e = eg & 255;
#pragma unroll
        for (int nt = 0; nt < 8; ++nt) {
            const int sb = sbi * 128 + nt * 16 + lr;
            const int s = sb >> 6, bgq = (sb >> 4) & 3, b_loc = sb & 15;
            float4 v;
            v.x = acc[mt][nt][0] + bia.x;
            v.y = acc[mt][nt][1] + bia.y;
            v.z = acc[mt][nt][2] + bia.z;
            v.w = acc[mt][nt][3] + bia.w;
            *(float4*)(dstb + ((size_t)s * 4 + bgq) * 4096 + (e >> 2) * 64 + b_loc * 4) = v;
        }
    }
}

// ---------------------------------------------------------------------------
// Kernel 2: MFMA recurrence. 8 blocks (dir*4 + bg), 256 thr (4 waves).
// This round: chunked epilogue (epi(mt) interleaved between MFMA chains so
// VALU hides under the matrix pipe), strength-reduced pointer walking for
// pre/out, #pragma unroll 2 so `cur` is static (hoisted LDS addresses).
// ---------------------------------------------------------------------------
#define CSWZ(row, off) ((off) ^ (((row) & 15) << 4))

__global__ __launch_bounds__(256, 1) void recur_mfma_kernel(
    const float* __restrict__ Wl, const float* __restrict__ Wr,
    const float* __restrict__ cl0, const float* __restrict__ cr0,
    const float* __restrict__ pre2_l, const float* __restrict__ pre2_r,
    unsigned short* __restrict__ outl, unsigned short* __restrict__ outr)
{
    __shared__ unsigned short cbf[2][16 * 256];  // [buf][b][e] swizzled rows

    const int dir = blockIdx.x >> 2;
    const int bg  = blockIdx.x & 3;
    const int b0  = bg * 16;
    const int tid  = threadIdx.x;
    const int wl   = tid >> 6;
    const int lane = tid & 63;
    const int col  = lane & 15;   // batch row
    const int g    = lane >> 4;

    const float* W   = dir ? Wr : Wl;
    const float* c0  = dir ? cr0 : cl0;
    const float* pre = dir ? pre2_r : pre2_l;
    unsigned short* out = dir ? outr : outl;

    // stationary W as A-side fragments: m=e = wl*64+mt*16+col ; k = ks*32+g*8+j
    bf16x8 wfrag[4][8];
#pragma unroll
    for (int mt = 0; mt < 4; ++mt)
#pragma unroll
        for (int ks = 0; ks < 8; ++ks) {
            const float* src = W + (size_t)(wl * 64 + mt * 16 + col) * DD
                                 + ks * 32 + g * 8;
            const float4 lo = *(const float4*)(src);
            const float4 hi = *(const float4*)(src + 4);
            ush8 p;
            p[0]=f2bf(lo.x); p[1]=f2bf(lo.y); p[2]=f2bf(lo.z); p[3]=f2bf(lo.w);
            p[4]=f2bf(hi.x); p[5]=f2bf(hi.y); p[6]=f2bf(hi.z); p[7]=f2bf(hi.w);
            wfrag[mt][ks] = *(bf16x8*)&p;
        }

    // init: cbf[0] = bf16(c0), out[t0] = bf16(c0)
    {
        const int blc = tid >> 4;
        const int ch  = tid & 15;
        const float* src = c0 + (size_t)(b0 + blc) * DD + ch * 16;
        const float4 v0 = *(const float4*)(src);
        const float4 v1 = *(const float4*)(src + 4);
        const float4 v2 = *(const float4*)(src + 8);
        const float4 v3 = *(const float4*)(src + 12);
        ush8 p0, p1;
        p0[0]=f2bf(v0.x); p0[1]=f2bf(v0.y); p0[2]=f2bf(v0.z); p0[3]=f2bf(v0.w);
        p0[4]=f2bf(v1.x); p0[5]=f2bf(v1.y); p0[6]=f2bf(v1.z); p0[7]=f2bf(v1.w);
        p1[0]=f2bf(v2.x); p1[1]=f2bf(v2.y); p1[2]=f2bf(v2.z); p1[3]=f2bf(v2.w);
        p1[4]=f2bf(v3.x); p1[5]=f2bf(v3.y); p1[6]=f2bf(v3.z); p1[7]=f2bf(v3.w);
        char* rowp = (char*)cbf[0] + blc * 512;
        *(ush8*)(rowp + CSWZ(blc, ch * 32))      = p0;
        *(ush8*)(rowp + CSWZ(blc, ch * 32 + 16)) = p1;
        const int t0 = dir ? 511 : 0;
        ush8* dst = (ush8*)(out + ((size_t)t0 * BB + b0 + blc) * DD + ch * 16);
        dst[0] = p0; dst[1] = p1;
    }

    // pre: strength-reduced pointer walk. lane-invariant offset + step +-16K.
    const int lpre = (wl * 16 + g) * 64 + col * 4;         // + q*64 per quarter
    const ptrdiff_t pstep = dir ? -(ptrdiff_t)16384 : (ptrdiff_t)16384;
    const float* p0 = pre + ((size_t)(dir ? 511 : 0) * 4 + bg) * 4096 + lpre;

    float4 pA0 = *(const float4*)(p0);
    float4 pA1 = *(const float4*)(p0 + 256);
    float4 pA2 = *(const float4*)(p0 + 512);
    float4 pA3 = *(const float4*)(p0 + 768);
    const float* p1p = p0 + pstep;
    float4 pB0 = *(const float4*)(p1p);
    float4 pB1 = *(const float4*)(p1p + 256);
    float4 pB2 = *(const float4*)(p1p + 512);
    float4 pB3 = *(const float4*)(p1p + 768);
    const float* pfetch = p0 + 2 * pstep;

    // out: strength-reduced pointer walk (per-lane base, +-BB*DD per step)
    unsigned short* oplane = out + (size_t)(dir ? 510 : 1) * BB * DD
                                 + (b0 + col) * DD + wl * 64 + g * 4;
    const ptrdiff_t ostep = (dir ? -(ptrdiff_t)1 : (ptrdiff_t)1) * (BB * DD);

    __syncthreads();

    int cur = 0;
#pragma unroll 2
    for (int k = 0; k < SS - 1; ++k) {
        // state B-fragments from cbf[cur] (lane&15 = b, k-dim = e)
        bf16x8 sfrag[8];
        {
            const char* rowp = (const char*)cbf[cur] + col * 512;
#pragma unroll
            for (int ks = 0; ks < 8; ++ks)
                sfrag[ks] = *(const bf16x8*)(rowp + CSWZ(col, ks * 64 + g * 16));
        }

        // issue pre loads for step k+2 (stay in flight across the barrier)
        const float4 pN0 = *(const float4*)(pfetch);
        const float4 pN1 = *(const float4*)(pfetch + 256);
        const float4 pN2 = *(const float4*)(pfetch + 512);
        const float4 pN3 = *(const float4*)(pfetch + 768);
        if (k < SS - 4) pfetch += pstep;

        char* nbuf = (char*)cbf[cur ^ 1] + col * 512;

        // per-mt epilogue: relu(acc+pre) -> LDS next-state + direct global out
        auto epi = [&](int mt, const float4 pv, const f32x4 a) {
            const float v0 = fmaxf(a[0] + pv.x, 0.f);
            const float v1 = fmaxf(a[1] + pv.y, 0.f);
            const float v2 = fmaxf(a[2] + pv.z, 0.f);
            const float v3 = fmaxf(a[3] + pv.w, 0.f);
            uint2 uu;
            uu.x = (unsigned)f2bf(v0) | ((unsigned)f2bf(v1) << 16);
            uu.y = (unsigned)f2bf(v2) | ((unsigned)f2bf(v3) << 16);
            const int eoff = (wl * 64 + mt * 16 + g * 4) * 2;
            *(uint2*)(nbuf + CSWZ(col, eoff)) = uu;
            *(uint2*)(oplane + mt * 16) = uu;
        };

        // chunked MFMA chains with epilogues interleaved (VALU hides under
        // the matrix pipe: epi(mt) is independent of chains mt+1..)
        f32x4 a0 = (f32x4)(0.f), a1 = (f32x4)(0.f);
        f32x4 a2 = (f32x4)(0.f), a3 = (f32x4)(0.f);
#pragma unroll
        for (int ks = 0; ks < 8; ++ks)
            a0 = __builtin_amdgcn_mfma_f32_16x16x32_bf16(wfrag[0][ks], sfrag[ks], a0, 0, 0, 0);
#pragma unroll
        for (int ks = 0; ks < 8; ++ks)
            a1 = __builtin_amdgcn_mfma_f32_16x16x32_bf16(wfrag[1][ks], sfrag[ks], a1, 0, 0, 0);
        epi(0, pA0, a0);
#pragma unroll
        for (int ks = 0; ks < 8; ++ks)
            a2 = __builtin_amdgcn_mfma_f32_16x16x32_bf16(wfrag[2][ks], sfrag[ks], a2, 0, 0, 0);
        epi(1, pA1, a1);
#pragma unroll
        for (int ks = 0; ks < 8; ++ks)
            a3 = __builtin_amdgcn_mfma_f32_16x16x32_bf16(wfrag[3][ks], sfrag[ks], a3, 0, 0, 0);
        epi(2, pA2, a2);
        epi(3, pA3, a3);

        pA0 = pB0; pA1 = pB1; pA2 = pB2; pA3 = pB3;
        pB0 = pN0; pB1 = pN1; pB2 = pN2; pB3 = pN3;
        oplane += ostep;

        // raw barrier: drain LDS ops only; global loads stay in flight
        asm volatile("s_waitcnt lgkmcnt(0)" ::: "memory");
        __builtin_amdgcn_s_barrier();
        asm volatile("" ::: "memory");
        cur ^= 1;
    }
}

// ---------------------------------------------------------------------------
// Kernel 3: conv(1x3D) + relu + maxpool, bf16 MFMA.
// left/right in [t][b][e] layout (same indexing form as e2).
// ---------------------------------------------------------------------------
#define KSTEP 64
#define NK 12
#define NST 4
#define APAD 72

__global__ __launch_bounds__(256) void conv_pool_kernel(
    const unsigned short* __restrict__ leftb,
    const unsigned short* __restrict__ e2,
    const unsigned short* __restrict__ rightb,
    const unsigned short* __restrict__ convwb,
    const float* __restrict__ conv_b,
    float* __restrict__ pooled)
{
    __shared__ unsigned short Abuf[2][128][APAD];
    __shared__ unsigned short Bbuf[2][128][APAD];
    __shared__ float red[4][128];

    const int b   = blockIdx.x >> 2;
    const int h0  = (blockIdx.x & 3) * 128;
    const int tid = threadIdx.x;
    const int wid = tid >> 6;
    const int lane = tid & 63;
    const int lr  = lane & 15;
    const int lk  = (lane >> 4) * 8;

    f32x4 acc[2][8];
    float pmax[8];
#pragma unroll
    for (int ht = 0; ht < 8; ++ht) {
        pmax[ht] = -INFINITY;
        acc[0][ht] = (f32x4)(0.f);
        acc[1][ht] = (f32x4)(0.f);
    }

    const int strow = tid >> 3;
    const int skc   = (tid & 7) * 8;

    auto stage = [&](int it, int buf) {
        const int stile = it / NK, kstep = it % NK;
        const int k0 = kstep * KSTEP;
        const int s0 = stile * 128;
        const unsigned short* asrc;
        int koff;
        if (k0 < DD)          { asrc = leftb;  koff = k0; }
        else if (k0 < 2 * DD) { asrc = e2;     koff = k0 - DD; }
        else                  { asrc = rightb; koff = k0 - 2 * DD; }
#pragma unroll
        for (int j = 0; j < 4; ++j) {
            const int row = strow + 32 * j;
            const int ss = s0 + row;
            *(bf16x8*)&Abuf[buf][row][skc] =
                *(const bf16x8*)(asrc + ((size_t)ss * BB + b) * DD + koff + skc);
            *(bf16x8*)&Bbuf[buf][row][skc] =
                *(const bf16x8*)(convwb + (size_t)(h0 + row) * K3D + k0 + skc);
        }
    };

    stage(0, 0);
    int cur = 0;
    for (int it = 0; it < NST * NK; ++it) {
        __syncthreads();
        if (it + 1 < NST * NK) stage(it + 1, cur ^ 1);

        const int wrow0 = wid * 32;
#pragma unroll
        for (int ks = 0; ks < 2; ++ks) {
            const int kk = ks * 32 + lk;
            const bf16x8 a0 = *(const bf16x8*)&Abuf[cur][wrow0 + lr][kk];
            const bf16x8 a1 = *(const bf16x8*)&Abuf[cur][wrow0 + 16 + lr][kk];
#pragma unroll
            for (int ht = 0; ht < 8; ++ht) {
                const bf16x8 bv = *(const bf16x8*)&Bbuf[cur][ht * 16 + lr][kk];
                acc[0][ht] = __builtin_amdgcn_mfma_f32_16x16x32_bf16(a0, bv, acc[0][ht], 0, 0, 0);
                acc[1][ht] = __builtin_amdgcn_mfma_f32_16x16x32_bf16(a1, bv, acc[1][ht], 0, 0, 0);
            }
        }
        if ((it % NK) == NK - 1) {
#pragma unroll
            for (int st = 0; st < 2; ++st)
#pragma unroll
                for (int ht = 0; ht < 8; ++ht) {
#pragma unroll
                    for (int r = 0; r < 4; ++r)
                        pmax[ht] = fmaxf(pmax[ht], acc[st][ht][r]);
                    acc[st][ht] = (f32x4)(0.f);
                }
        }
        cur ^= 1;
    }

#pragma unroll
    for (int ht = 0; ht < 8; ++ht) {
        float m = pmax[ht];
        m = fmaxf(m, __shfl_xor(m, 16));
        m = fmaxf(m, __shfl_xor(m, 32));
        if (lane < 16) red[wid][ht * 16 + lane] = m;
    }
    __syncthreads();
    if (tid < 128) {
        const float m = fmaxf(fmaxf(red[0][tid], red[1][tid]),
                              fmaxf(red[2][tid], red[3][tid]));
        pooled[(size_t)b * HH + h0 + tid] = fmaxf(m + conv_b[h0 + tid], 0.f);
    }
}

// ---------------------------------------------------------------------------
// Kernel 4: final FC (unchanged).
// ---------------------------------------------------------------------------
__global__ void fc_kernel(const float* __restrict__ pooled,
                          const float* __restrict__ fc_w,
                          const float* __restrict__ fc_b,
                          float* __restrict__ out)
{
    const int t = threadIdx.x;
    if (t >= BB * NCLS) return;
    const int b = t / NCLS, c = t % NCLS;
    float acc = fc_b[c];
    for (int h = 0; h < HH; ++h)
        acc += pooled[(size_t)b * HH + h] * fc_w[(size_t)c * HH + h];
    out[b * NCLS + c] = acc;
}

// ---------------------------------------------------------------------------
extern "C" void kernel_launch(void* const* d_in, const int* in_sizes, int n_in,
                              void* d_out, int out_size, void* d_ws, size_t ws_size,
                              hipStream_t stream)
{
    const int*   x       = (const int*)  d_in[0];
    const float* embed_w = (const float*)d_in[1];
    const float* Wl      = (const float*)d_in[2];
    const float* bl      = (const float*)d_in[3];
    const float* Wsl     = (const float*)d_in[4];
    const float* bsl     = (const float*)d_in[5];
    const float* Wr      = (const float*)d_in[6];
    const float* br      = (const float*)d_in[7];
    const float* Wsr     = (const float*)d_in[8];
    const float* bsr     = (const float*)d_in[9];
    const float* conv_w  = (const float*)d_in[10];
    const float* conv_b  = (const float*)d_in[11];
    const float* fc_w    = (const float*)d_in[12];
    const float* fc_b    = (const float*)d_in[13];
    const float* cl0     = (const float*)d_in[14];
    const float* cr0     = (const float*)d_in[15];
    float* out = (float*)d_out;

    char* ws = (char*)d_ws;
    const size_t SZf = (size_t)SS * BB * DD * sizeof(float);           // 33.55 MB
    const size_t SZh = (size_t)SS * BB * DD * sizeof(unsigned short);  // 16.78 MB
    float*          pre2_l = (float*)(ws);
    float*          pre2_r = (float*)(ws + SZf);
    unsigned short* leftb  = (unsigned short*)(ws + 2 * SZf);
    unsigned short* rightb = (unsigned short*)(ws + 2 * SZf + SZh);
    unsigned short* e2     = (unsigned short*)(ws + 2 * SZf + 2 * SZh);
    unsigned short* convwb = (unsigned short*)(ws + 2 * SZf + 3 * SZh);
    unsigned short* wscat  = (unsigned short*)(ws + 2 * SZf + 3 * SZh + (size_t)HH * K3D * 2);
    float*          biascat= (float*)(ws + 2 * SZf + 3 * SZh + (size_t)HH * K3D * 2 + (size_t)512 * DD * 2);
    float*          pooled = (float*)(ws + 2 * SZf + 3 * SZh + (size_t)HH * K3D * 2 + (size_t)512 * DD * 2 + 2048);

    prep_kernel<<<257, 256, 0, stream>>>(conv_w, Wsl, Wsr, bsl, bl, bsr, br,
                                         convwb, wscat, biascat);

    gather_e_kernel<<<(BB * SS * DD / 8) / 256, 256, 0, stream>>>(x, embed_w, e2);

    pre_mfma_kernel<<<1024, 256, 0, stream>>>(wscat, e2, biascat, pre2_l, pre2_r);

    recur_mfma_kernel<<<8, 256, 0, stream>>>(
        Wl, Wr, cl0, cr0, pre2_l, pre2_r, leftb, rightb);

    conv_pool_kernel<<<BB * (HH / 128), 256, 0, stream>>>(
        leftb, e2, rightb, convwb, conv_b, pooled);

    fc_kernel<<<1, BB * NCLS, 0, stream>>>(pooled, fc_w, fc_b, out);
}

// Round 8
// 472.651 us; speedup vs baseline: 1.4313x; 1.0039x over previous
//
#include <hip/hip_runtime.h>
#include <hip/hip_bf16.h>

#define VOCAB 50000
#define DD 256
#define NCLS 10
#define BB 64
#define SS 512
#define HH 512
#define K3D 768

typedef __attribute__((ext_vector_type(8))) short bf16x8;
typedef __attribute__((ext_vector_type(8))) unsigned short ush8;
typedef __attribute__((ext_vector_type(4))) float f32x4;

static __device__ __forceinline__ unsigned short f2bf(float f) {
    __hip_bfloat16 h = __float2bfloat16(f);
    return *reinterpret_cast<unsigned short*>(&h);
}

// ---------------------------------------------------------------------------
// Kernel P: prep — convert conv_w, build Wscat (bf16 concat Wsl|Wsr), biascat.
// ---------------------------------------------------------------------------
__global__ __launch_bounds__(256) void prep_kernel(
    const float* __restrict__ conv_w,
    const float* __restrict__ Wsl, const float* __restrict__ Wsr,
    const float* __restrict__ bsl, const float* __restrict__ bl,
    const float* __restrict__ bsr, const float* __restrict__ br,
    unsigned short* __restrict__ convwb,
    unsigned short* __restrict__ wscat,
    float* __restrict__ biascat)
{
    const int bid = blockIdx.x;
    if (bid < 192) {
        const int g = bid * 256 + threadIdx.x;
        const float* src = conv_w + (size_t)g * 8;
        const float4 v0 = *(const float4*)(src);
        const float4 v1 = *(const float4*)(src + 4);
        ush8 o;
        o[0]=f2bf(v0.x); o[1]=f2bf(v0.y); o[2]=f2bf(v0.z); o[3]=f2bf(v0.w);
        o[4]=f2bf(v1.x); o[5]=f2bf(v1.y); o[6]=f2bf(v1.z); o[7]=f2bf(v1.w);
        *(ush8*)(convwb + (size_t)g * 8) = o;
    } else if (bid < 256) {
        const int g = (bid - 192) * 256 + threadIdx.x;
        const int row = g >> 5, d0 = (g & 31) * 8;
        const float* src = (row < 256 ? Wsl + (size_t)row * DD
                                      : Wsr + (size_t)(row - 256) * DD) + d0;
        const float4 v0 = *(const float4*)(src);
        const float4 v1 = *(const float4*)(src + 4);
        ush8 o;
        o[0]=f2bf(v0.x); o[1]=f2bf(v0.y); o[2]=f2bf(v0.z); o[3]=f2bf(v0.w);
        o[4]=f2bf(v1.x); o[5]=f2bf(v1.y); o[6]=f2bf(v1.z); o[7]=f2bf(v1.w);
        *(ush8*)(wscat + (size_t)g * 8) = o;
    } else {
        for (int i = threadIdx.x; i < 512; i += 256)
            biascat[i] = (i < 256) ? (bsl[i] + bl[i]) : (bsr[i - 256] + br[i - 256]);
    }
}

// ---------------------------------------------------------------------------
// Kernel 0: gather embedding rows -> bf16 e2[s*64+b][d]
// ---------------------------------------------------------------------------
__global__ __launch_bounds__(256) void gather_e_kernel(
    const int* __restrict__ x, const float* __restrict__ embed_w,
    unsigned short* __restrict__ e2)
{
    const int g = blockIdx.x * 256 + threadIdx.x;
    const int bs = g >> 5;                         // b*S + s
    const int b = bs >> 9, s = bs & (SS - 1);
    const int d0 = (g & 31) * 8;
    const float* src = embed_w + (size_t)x[bs] * DD + d0;
    const float4 v0 = *(const float4*)(src);
    const float4 v1 = *(const float4*)(src + 4);
    ush8 o;
    o[0]=f2bf(v0.x); o[1]=f2bf(v0.y); o[2]=f2bf(v0.z); o[3]=f2bf(v0.w);
    o[4]=f2bf(v1.x); o[5]=f2bf(v1.y); o[6]=f2bf(v1.z); o[7]=f2bf(v1.w);
    *(ush8*)(e2 + ((size_t)s * BB + b) * DD + d0) = o;
}

// ---------------------------------------------------------------------------
// Kernel 1: pre-GEMM as bf16 MFMA. Output in the recurrence's pre2 slot
// layout (fp32), biases folded. grid = 1024 blocks, 256 threads.
// ---------------------------------------------------------------------------
#define PPAD 72

__global__ __launch_bounds__(256) void pre_mfma_kernel(
    const unsigned short* __restrict__ wscat,
    const unsigned short* __restrict__ e2,
    const float* __restrict__ biascat,
    float* __restrict__ pre2_l, float* __restrict__ pre2_r)
{
    __shared__ unsigned short Abuf[2][128][PPAD];
    __shared__ unsigned short Bbuf[2][128][PPAD];

    const int mi  = blockIdx.x & 3;
    const int sbi = blockIdx.x >> 2;
    const int tid = threadIdx.x;
    const int w = tid >> 6, lane = tid & 63;
    const int lr = lane & 15, g = lane >> 4;
    const int lk = g * 8;

    f32x4 acc[2][8];
#pragma unroll
    for (int mt = 0; mt < 2; ++mt)
#pragma unroll
        for (int nt = 0; nt < 8; ++nt) acc[mt][nt] = (f32x4)(0.f);

    const int strow = tid >> 3;
    const int skc   = (tid & 7) * 8;

    auto stage = [&](int ks, int buf) {
        const int k0 = ks * 64;
#pragma unroll
        for (int j = 0; j < 4; ++j) {
            const int row = strow + 32 * j;
            *(bf16x8*)&Abuf[buf][row][skc] =
                *(const bf16x8*)(wscat + (size_t)(mi * 128 + row) * DD + k0 + skc);
            *(bf16x8*)&Bbuf[buf][row][skc] =
                *(const bf16x8*)(e2 + (size_t)(sbi * 128 + row) * DD + k0 + skc);
        }
    };

    stage(0, 0);
    int cur = 0;
    for (int ks = 0; ks < 4; ++ks) {
        __syncthreads();
        if (ks + 1 < 4) stage(ks + 1, cur ^ 1);
#pragma unroll
        for (int k2 = 0; k2 < 2; ++k2) {
            const int kk = k2 * 32 + lk;
            const bf16x8 a0 = *(const bf16x8*)&Abuf[cur][w * 32 + lr][kk];
            const bf16x8 a1 = *(const bf16x8*)&Abuf[cur][w * 32 + 16 + lr][kk];
#pragma unroll
            for (int nt = 0; nt < 8; ++nt) {
                const bf16x8 bv = *(const bf16x8*)&Bbuf[cur][nt * 16 + lr][kk];
                acc[0][nt] = __builtin_amdgcn_mfma_f32_16x16x32_bf16(a0, bv, acc[0][nt], 0, 0, 0);
                acc[1][nt] = __builtin_amdgcn_mfma_f32_16x16x32_bf16(a1, bv, acc[1][nt], 0, 0, 0);
            }
        }
        cur ^= 1;
    }

#pragma unroll
    for (int mt = 0; mt < 2; ++mt) {
        const int eg = mi * 128 + w * 32 + mt * 16 + g * 4;
        const float4 bia = *(const float4*)(biascat + eg);
        float* dstb = (eg >= 256) ? pre2_r : pre2_l;
        const int e = eg & 255;
#pragma unroll
        for (int nt = 0; nt < 8; ++nt) {
            const int sb = sbi * 128 + nt * 16 + lr;
            const int s = sb >> 6, bgq = (sb >> 4) & 3, b_loc = sb & 15;
            float4 v;
            v.x = acc[mt][nt][0] + bia.x;
            v.y = acc[mt][nt][1] + bia.y;
            v.z = acc[mt][nt][2] + bia.z;
            v.w = acc[mt][nt][3] + bia.w;
            *(float4*)(dstb + ((size_t)s * 4 + bgq) * 4096 + (e >> 2) * 64 + b_loc * 4) = v;
        }
    }
}

// ---------------------------------------------------------------------------
// Kernel 2: MFMA recurrence. 8 blocks (dir*4 + bg), 256 thr (4 waves).
// This round: per-wave k-tile rotation (wave wl starts at tile 2*wl; rotation
// carried in global/LDS ADDRESSES, register indices static) so the 4 waves'
// LDS reads and MFMA phases stagger instead of contending; dist-2 MFMA
// interleave in two half-rounds with chunked epilogues; setprio around MFMA.
// ---------------------------------------------------------------------------
#define CSWZ(row, off) ((off) ^ (((row) & 15) << 4))

__global__ __launch_bounds__(256, 1) void recur_mfma_kernel(
    const float* __restrict__ Wl, const float* __restrict__ Wr,
    const float* __restrict__ cl0, const float* __restrict__ cr0,
    const float* __restrict__ pre2_l, const float* __restrict__ pre2_r,
    unsigned short* __restrict__ outl, unsigned short* __restrict__ outr)
{
    __shared__ unsigned short cbf[2][16 * 256];  // [buf][b][e] swizzled rows

    const int dir = blockIdx.x >> 2;
    const int bg  = blockIdx.x & 3;
    const int b0  = bg * 16;
    const int tid  = threadIdx.x;
    const int wl   = tid >> 6;
    const int lane = tid & 63;
    const int col  = lane & 15;   // batch row
    const int g    = lane >> 4;

    const float* W   = dir ? Wr : Wl;
    const float* c0  = dir ? cr0 : cl0;
    const float* pre = dir ? pre2_r : pre2_l;
    unsigned short* out = dir ? outr : outl;

    // stationary W as A-side fragments, PRE-ROTATED by 2*wl k-tiles:
    // wfrag[mt][i] holds k-tile kt=(i+2*wl)&7; m=e = wl*64+mt*16+col.
    bf16x8 wfrag[4][8];
#pragma unroll
    for (int mt = 0; mt < 4; ++mt)
#pragma unroll
        for (int i = 0; i < 8; ++i) {
            const int kt = (i + 2 * wl) & 7;
            const float* src = W + (size_t)(wl * 64 + mt * 16 + col) * DD
                                 + kt * 32 + g * 8;
            const float4 lo = *(const float4*)(src);
            const float4 hi = *(const float4*)(src + 4);
            ush8 p;
            p[0]=f2bf(lo.x); p[1]=f2bf(lo.y); p[2]=f2bf(lo.z); p[3]=f2bf(lo.w);
            p[4]=f2bf(hi.x); p[5]=f2bf(hi.y); p[6]=f2bf(hi.z); p[7]=f2bf(hi.w);
            wfrag[mt][i] = *(bf16x8*)&p;
        }

    // rotated sfrag byte-offsets (per-lane, hoisted; static reg indices)
    int soff[8];
#pragma unroll
    for (int i = 0; i < 8; ++i) {
        const int kt = (i + 2 * wl) & 7;
        soff[i] = CSWZ(col, kt * 64 + g * 16);
    }

    // init: cbf[0] = bf16(c0), out[t0] = bf16(c0)
    {
        const int blc = tid >> 4;
        const int ch  = tid & 15;
        const float* src = c0 + (size_t)(b0 + blc) * DD + ch * 16;
        const float4 v0 = *(const float4*)(src);
        const float4 v1 = *(const float4*)(src + 4);
        const float4 v2 = *(const float4*)(src + 8);
        const float4 v3 = *(const float4*)(src + 12);
        ush8 p0, p1;
        p0[0]=f2bf(v0.x); p0[1]=f2bf(v0.y); p0[2]=f2bf(v0.z); p0[3]=f2bf(v0.w);
        p0[4]=f2bf(v1.x); p0[5]=f2bf(v1.y); p0[6]=f2bf(v1.z); p0[7]=f2bf(v1.w);
        p1[0]=f2bf(v2.x); p1[1]=f2bf(v2.y); p1[2]=f2bf(v2.z); p1[3]=f2bf(v2.w);
        p1[4]=f2bf(v3.x); p1[5]=f2bf(v3.y); p1[6]=f2bf(v3.z); p1[7]=f2bf(v3.w);
        char* rowp = (char*)cbf[0] + blc * 512;
        *(ush8*)(rowp + CSWZ(blc, ch * 32))      = p0;
        *(ush8*)(rowp + CSWZ(blc, ch * 32 + 16)) = p1;
        const int t0 = dir ? 511 : 0;
        ush8* dst = (ush8*)(out + ((size_t)t0 * BB + b0 + blc) * DD + ch * 16);
        dst[0] = p0; dst[1] = p1;
    }

    // pre: strength-reduced pointer walk. lane-invariant offset + step +-16K.
    const int lpre = (wl * 16 + g) * 64 + col * 4;
    const ptrdiff_t pstep = dir ? -(ptrdiff_t)16384 : (ptrdiff_t)16384;
    const float* p0 = pre + ((size_t)(dir ? 511 : 0) * 4 + bg) * 4096 + lpre;

    float4 pA0 = *(const float4*)(p0);
    float4 pA1 = *(const float4*)(p0 + 256);
    float4 pA2 = *(const float4*)(p0 + 512);
    float4 pA3 = *(const float4*)(p0 + 768);
    const float* p1p = p0 + pstep;
    float4 pB0 = *(const float4*)(p1p);
    float4 pB1 = *(const float4*)(p1p + 256);
    float4 pB2 = *(const float4*)(p1p + 512);
    float4 pB3 = *(const float4*)(p1p + 768);
    const float* pfetch = p0 + 2 * pstep;

    // out: strength-reduced pointer walk (per-lane base, +-BB*DD per step)
    unsigned short* oplane = out + (size_t)(dir ? 510 : 1) * BB * DD
                                 + (b0 + col) * DD + wl * 64 + g * 4;
    const ptrdiff_t ostep = (dir ? -(ptrdiff_t)1 : (ptrdiff_t)1) * (BB * DD);

    __syncthreads();

    int cur = 0;
#pragma unroll 2
    for (int k = 0; k < SS - 1; ++k) {
        // state B-fragments from cbf[cur], rotated read order (runtime addr OK)
        bf16x8 sfrag[8];
        {
            const char* rowp = (const char*)cbf[cur] + col * 512;
#pragma unroll
            for (int i = 0; i < 8; ++i)
                sfrag[i] = *(const bf16x8*)(rowp + soff[i]);
        }

        // issue pre loads for step k+2 (stay in flight across the barrier)
        const float4 pN0 = *(const float4*)(pfetch);
        const float4 pN1 = *(const float4*)(pfetch + 256);
        const float4 pN2 = *(const float4*)(pfetch + 512);
        const float4 pN3 = *(const float4*)(pfetch + 768);
        if (k < SS - 4) pfetch += pstep;

        char* nbuf = (char*)cbf[cur ^ 1] + col * 512;

        // per-mt epilogue: relu(acc+pre) -> LDS next-state + direct global out
        auto epi = [&](int mt, const float4 pv, const f32x4 a) {
            const float v0 = fmaxf(a[0] + pv.x, 0.f);
            const float v1 = fmaxf(a[1] + pv.y, 0.f);
            const float v2 = fmaxf(a[2] + pv.z, 0.f);
            const float v3 = fmaxf(a[3] + pv.w, 0.f);
            uint2 uu;
            uu.x = (unsigned)f2bf(v0) | ((unsigned)f2bf(v1) << 16);
            uu.y = (unsigned)f2bf(v2) | ((unsigned)f2bf(v3) << 16);
            const int eoff = (wl * 64 + mt * 16 + g * 4) * 2;
            *(uint2*)(nbuf + CSWZ(col, eoff)) = uu;
            *(uint2*)(oplane + mt * 16) = uu;
        };

        // half-round 1: chains 0,1 interleaved (dep distance 2)
        f32x4 a0 = (f32x4)(0.f), a1 = (f32x4)(0.f);
        __builtin_amdgcn_s_setprio(1);
#pragma unroll
        for (int i = 0; i < 8; ++i) {
            a0 = __builtin_amdgcn_mfma_f32_16x16x32_bf16(wfrag[0][i], sfrag[i], a0, 0, 0, 0);
            a1 = __builtin_amdgcn_mfma_f32_16x16x32_bf16(wfrag[1][i], sfrag[i], a1, 0, 0, 0);
        }
        __builtin_amdgcn_s_setprio(0);
        epi(0, pA0, a0);
        epi(1, pA1, a1);

        // half-round 2: chains 2,3 interleaved (epi 0/1 hides under these)
        f32x4 a2 = (f32x4)(0.f), a3 = (f32x4)(0.f);
        __builtin_amdgcn_s_setprio(1);
#pragma unroll
        for (int i = 0; i < 8; ++i) {
            a2 = __builtin_amdgcn_mfma_f32_16x16x32_bf16(wfrag[2][i], sfrag[i], a2, 0, 0, 0);
            a3 = __builtin_amdgcn_mfma_f32_16x16x32_bf16(wfrag[3][i], sfrag[i], a3, 0, 0, 0);
        }
        __builtin_amdgcn_s_setprio(0);
        epi(2, pA2, a2);
        epi(3, pA3, a3);

        pA0 = pB0; pA1 = pB1; pA2 = pB2; pA3 = pB3;
        pB0 = pN0; pB1 = pN1; pB2 = pN2; pB3 = pN3;
        oplane += ostep;

        // raw barrier: drain LDS ops only; global loads stay in flight
        asm volatile("s_waitcnt lgkmcnt(0)" ::: "memory");
        __builtin_amdgcn_s_barrier();
        asm volatile("" ::: "memory");
        cur ^= 1;
    }
}

// ---------------------------------------------------------------------------
// Kernel 3: conv(1x3D) + relu + maxpool, bf16 MFMA.
// left/right in [t][b][e] layout (same indexing form as e2).
// ---------------------------------------------------------------------------
#define KSTEP 64
#define NK 12
#define NST 4
#define APAD 72

__global__ __launch_bounds__(256) void conv_pool_kernel(
    const unsigned short* __restrict__ leftb,
    const unsigned short* __restrict__ e2,
    const unsigned short* __restrict__ rightb,
    const unsigned short* __restrict__ convwb,
    const float* __restrict__ conv_b,
    float* __restrict__ pooled)
{
    __shared__ unsigned short Abuf[2][128][APAD];
    __shared__ unsigned short Bbuf[2][128][APAD];
    __shared__ float red[4][128];

    const int b   = blockIdx.x >> 2;
    const int h0  = (blockIdx.x & 3) * 128;
    const int tid = threadIdx.x;
    const int wid = tid >> 6;
    const int lane = tid & 63;
    const int lr  = lane & 15;
    const int lk  = (lane >> 4) * 8;

    f32x4 acc[2][8];
    float pmax[8];
#pragma unroll
    for (int ht = 0; ht < 8; ++ht) {
        pmax[ht] = -INFINITY;
        acc[0][ht] = (f32x4)(0.f);
        acc[1][ht] = (f32x4)(0.f);
    }

    const int strow = tid >> 3;
    const int skc   = (tid & 7) * 8;

    auto stage = [&](int it, int buf) {
        const int stile = it / NK, kstep = it % NK;
        const int k0 = kstep * KSTEP;
        const int s0 = stile * 128;
        const unsigned short* asrc;
        int koff;
        if (k0 < DD)          { asrc = leftb;  koff = k0; }
        else if (k0 < 2 * DD) { asrc = e2;     koff = k0 - DD; }
        else                  { asrc = rightb; koff = k0 - 2 * DD; }
#pragma unroll
        for (int j = 0; j < 4; ++j) {
            const int row = strow + 32 * j;
            const int ss = s0 + row;
            *(bf16x8*)&Abuf[buf][row][skc] =
                *(const bf16x8*)(asrc + ((size_t)ss * BB + b) * DD + koff + skc);
            *(bf16x8*)&Bbuf[buf][row][skc] =
                *(const bf16x8*)(convwb + (size_t)(h0 + row) * K3D + k0 + skc);
        }
    };

    stage(0, 0);
    int cur = 0;
    for (int it = 0; it < NST * NK; ++it) {
        __syncthreads();
        if (it + 1 < NST * NK) stage(it + 1, cur ^ 1);

        const int wrow0 = wid * 32;
#pragma unroll
        for (int ks = 0; ks < 2; ++ks) {
            const int kk = ks * 32 + lk;
            const bf16x8 a0 = *(const bf16x8*)&Abuf[cur][wrow0 + lr][kk];
            const bf16x8 a1 = *(const bf16x8*)&Abuf[cur][wrow0 + 16 + lr][kk];
#pragma unroll
            for (int ht = 0; ht < 8; ++ht) {
                const bf16x8 bv = *(const bf16x8*)&Bbuf[cur][ht * 16 + lr][kk];
                acc[0][ht] = __builtin_amdgcn_mfma_f32_16x16x32_bf16(a0, bv, acc[0][ht], 0, 0, 0);
                acc[1][ht] = __builtin_amdgcn_mfma_f32_16x16x32_bf16(a1, bv, acc[1][ht], 0, 0, 0);
            }
        }
        if ((it % NK) == NK - 1) {
#pragma unroll
            for (int st = 0; st < 2; ++st)
#pragma unroll
                for (int ht = 0; ht < 8; ++ht) {
#pragma unroll
                    for (int r = 0; r < 4; ++r)
                        pmax[ht] = fmaxf(pmax[ht], acc[st][ht][r]);
                    acc[st][ht] = (f32x4)(0.f);
                }
        }
        cur ^= 1;
    }

#pragma unroll
    for (int ht = 0; ht < 8; ++ht) {
        float m = pmax[ht];
        m = fmaxf(m, __shfl_xor(m, 16));
        m = fmaxf(m, __shfl_xor(m, 32));
        if (lane < 16) red[wid][ht * 16 + lane] = m;
    }
    __syncthreads();
    if (tid < 128) {
        const float m = fmaxf(fmaxf(red[0][tid], red[1][tid]),
                              fmaxf(red[2][tid], red[3][tid]));
        pooled[(size_t)b * HH + h0 + tid] = fmaxf(m + conv_b[h0 + tid], 0.f);
    }
}

// ---------------------------------------------------------------------------
// Kernel 4: final FC (unchanged).
// ---------------------------------------------------------------------------
__global__ void fc_kernel(const float* __restrict__ pooled,
                          const float* __restrict__ fc_w,
                          const float* __restrict__ fc_b,
                          float* __restrict__ out)
{
    const int t = threadIdx.x;
    if (t >= BB * NCLS) return;
    const int b = t / NCLS, c = t % NCLS;
    float acc = fc_b[c];
    for (int h = 0; h < HH; ++h)
        acc += pooled[(size_t)b * HH + h] * fc_w[(size_t)c * HH + h];
    out[b * NCLS + c] = acc;
}

// ---------------------------------------------------------------------------
extern "C" void kernel_launch(void* const* d_in, const int* in_sizes, int n_in,
                              void* d_out, int out_size, void* d_ws, size_t ws_size,
                              hipStream_t stream)
{
    const int*   x       = (const int*)  d_in[0];
    const float* embed_w = (const float*)d_in[1];
    const float* Wl      = (const float*)d_in[2];
    const float* bl      = (const float*)d_in[3];
    const float* Wsl     = (const float*)d_in[4];
    const float* bsl     = (const float*)d_in[5];
    const float* Wr      = (const float*)d_in[6];
    const float* br      = (const float*)d_in[7];
    const float* Wsr     = (const float*)d_in[8];
    const float* bsr     = (const float*)d_in[9];
    const float* conv_w  = (const float*)d_in[10];
    const float* conv_b  = (const float*)d_in[11];
    const float* fc_w    = (const float*)d_in[12];
    const float* fc_b    = (const float*)d_in[13];
    const float* cl0     = (const float*)d_in[14];
    const float* cr0     = (const float*)d_in[15];
    float* out = (float*)d_out;

    char* ws = (char*)d_ws;
    const size_t SZf = (size_t)SS * BB * DD * sizeof(float);           // 33.55 MB
    const size_t SZh = (size_t)SS * BB * DD * sizeof(unsigned short);  // 16.78 MB
    float*          pre2_l = (float*)(ws);
    float*          pre2_r = (float*)(ws + SZf);
    unsigned short* leftb  = (unsigned short*)(ws + 2 * SZf);
    unsigned short* rightb = (unsigned short*)(ws + 2 * SZf + SZh);
    unsigned short* e2     = (unsigned short*)(ws + 2 * SZf + 2 * SZh);
    unsigned short* convwb = (unsigned short*)(ws + 2 * SZf + 3 * SZh);
    unsigned short* wscat  = (unsigned short*)(ws + 2 * SZf + 3 * SZh + (size_t)HH * K3D * 2);
    float*          biascat= (float*)(ws + 2 * SZf + 3 * SZh + (size_t)HH * K3D * 2 + (size_t)512 * DD * 2);
    float*          pooled = (float*)(ws + 2 * SZf + 3 * SZh + (size_t)HH * K3D * 2 + (size_t)512 * DD * 2 + 2048);

    prep_kernel<<<257, 256, 0, stream>>>(conv_w, Wsl, Wsr, bsl, bl, bsr, br,
                                         convwb, wscat, biascat);

    gather_e_kernel<<<(BB * SS * DD / 8) / 256, 256, 0, stream>>>(x, embed_w, e2);

    pre_mfma_kernel<<<1024, 256, 0, stream>>>(wscat, e2, biascat, pre2_l, pre2_r);

    recur_mfma_kernel<<<8, 256, 0, stream>>>(
        Wl, Wr, cl0, cr0, pre2_l, pre2_r, leftb, rightb);

    conv_pool_kernel<<<BB * (HH / 128), 256, 0, stream>>>(
        leftb, e2, rightb, convwb, conv_b, pooled);

    fc_kernel<<<1, BB * NCLS, 0, stream>>>(pooled, fc_w, fc_b, out);
}